// Round 5
// baseline (36643.896 us; speedup 1.0000x reference)
//
#include <hip/hip_runtime.h>

#define TT 8192
#define DD 2048
#define NWG 256
#define RPW 8           // rows of h per workgroup
#define NTH 256
#define NREP 4          // replica lines per chunk (spread LLC poll hotspot)

typedef unsigned long long u64;
#define SIGN2 0x8000000080000000ULL

// ---------------- Phase 1: pre = x @ W1^T + b1  (M=TT, N=DD, K=DD) ----------
#define BM 128
#define BN 128
#define BK 16

__global__ __launch_bounds__(NTH)
void gemm_abt_bias(const float* __restrict__ A, const float* __restrict__ B,
                   const float* __restrict__ bias, float* __restrict__ C,
                   int M, int N, int K) {
  __shared__ float As[BK][BM + 4];
  __shared__ float Bs[BK][BN + 4];
  const int ntile = N / BN;
  const int bn = blockIdx.x % ntile;
  const int bm = blockIdx.x / ntile;
  const int tid = (int)threadIdx.x;
  const int tx = tid & 15;
  const int ty = tid >> 4;

  float acc[8][8];
#pragma unroll
  for (int i = 0; i < 8; ++i)
#pragma unroll
    for (int j = 0; j < 8; ++j) acc[i][j] = 0.f;

  for (int kt = 0; kt < K; kt += BK) {
#pragma unroll
    for (int i = 0; i < 2; ++i) {
      int f = tid + i * 256;
      int row = f >> 2, c4 = f & 3;
      const float4 av = *(const float4*)(A + (size_t)(bm * BM + row) * K + kt + c4 * 4);
      As[c4 * 4 + 0][row] = av.x; As[c4 * 4 + 1][row] = av.y;
      As[c4 * 4 + 2][row] = av.z; As[c4 * 4 + 3][row] = av.w;
      const float4 bv = *(const float4*)(B + (size_t)(bn * BN + row) * K + kt + c4 * 4);
      Bs[c4 * 4 + 0][row] = bv.x; Bs[c4 * 4 + 1][row] = bv.y;
      Bs[c4 * 4 + 2][row] = bv.z; Bs[c4 * 4 + 3][row] = bv.w;
    }
    __syncthreads();
#pragma unroll
    for (int kk = 0; kk < BK; ++kk) {
      float a[8], b[8];
      *(float4*)&a[0] = *(const float4*)&As[kk][ty * 8];
      *(float4*)&a[4] = *(const float4*)&As[kk][ty * 8 + 4];
      *(float4*)&b[0] = *(const float4*)&Bs[kk][tx * 8];
      *(float4*)&b[4] = *(const float4*)&Bs[kk][tx * 8 + 4];
#pragma unroll
      for (int i = 0; i < 8; ++i)
#pragma unroll
        for (int j = 0; j < 8; ++j) acc[i][j] += a[i] * b[j];
    }
    __syncthreads();
  }

  const int col0 = bn * BN + tx * 8;
  const float4 bv0 = *(const float4*)(bias + col0);
  const float4 bv1 = *(const float4*)(bias + col0 + 4);
#pragma unroll
  for (int i = 0; i < 8; ++i) {
    float* crow = C + (size_t)(bm * BM + ty * 8 + i) * N + col0;
    float4 v0 = { acc[i][0] + bv0.x, acc[i][1] + bv0.y, acc[i][2] + bv0.z, acc[i][3] + bv0.w };
    float4 v1 = { acc[i][4] + bv1.x, acc[i][5] + bv1.y, acc[i][6] + bv1.z, acc[i][7] + bv1.w };
    *(float4*)(crow) = v0;
    *(float4*)(crow + 4) = v1;
  }
}

// ---------------- Phase 2: persistent recurrent kernel ----------------------
__device__ __forceinline__ float wave_sum(float v) {
#pragma unroll
  for (int off = 32; off > 0; off >>= 1) v += __shfl_down(v, off, 64);
  return v;
}

__device__ __forceinline__ u64 aload(const u64* p) {
  return __hip_atomic_load(p, __ATOMIC_RELAXED, __HIP_MEMORY_SCOPE_AGENT);
}
__device__ __forceinline__ void astore(u64* p, u64 v) {
  __hip_atomic_store(p, v, __ATOMIC_RELAXED, __HIP_MEMORY_SCOPE_AGENT);
}

// Sync protocol (relaxed agent-scope only; parity tags in sign bits of the
// ReLU-nonnegative h values; slot = t&1, tag = (t>>1)&1):
//  * Message unit = one FULL 128-B line per (WG, replica): the WG's 4 tagged
//    u64s (8 h values) replicated 4x within the line. 16 combine-threads emit
//    it as ONE coalesced full-line store per replica -> no partial-line RMW
//    at the LLC, no merge-delay on visibility.
//  * hbuf layout (u64 units): line(slot,rep,wg) = ((slot*NREP+rep)*NWG+wg)*16.
//    Consumer (WG w, thread tid) polls producer-line (slot, w&3, tid) at copy
//    (w>>2)&3 -> u64s [copy*4, copy*4+4). <=16 pollers per 32-B copy.
//  * Each thread consumes EXACTLY the 8 h values it polls (k-slice 8*tid);
//    W2 for all 8 WG-rows x that slice is register-pinned (ALL pointer params
//    are __restrict__ -- without it the in-loop hbuf stores alias W2 and the
//    compiler re-loads W2 every step; R3/R4's VGPR_Count=60 proved that).
//  * ABA/slot-reuse safety (induction): any h_{t+2} chunk existing implies its
//    producer detected ALL of h_{t+1}, hence every WG stored h_{t+1}, hence
//    every WG finished its step-t reads. Tag check and consumption use the
//    same registers (no re-read).
//  * Anti-poison: slot0 lines = 0x00 (tag 0; first tenant h_2 expects tag 1),
//    slot1 lines = 0xAA (tag 1; first tenant h_1 expects tag 0).
__global__ void __launch_bounds__(NTH, 1)
recurrent_kernel(const float* __restrict__ h0,
                 const float* __restrict__ W2,
                 const float* __restrict__ b2,
                 const float* __restrict__ pre,
                 const float* __restrict__ Wf,
                 const float* __restrict__ bf,
                 float* __restrict__ out,
                 u64* __restrict__ hbU) {   // 2*NREP*NWG lines (256 KB)
  __shared__ float partial[2][4][8];   // [t&1][wave][row]
  __shared__ float hs[DD];             // epilogue only

  const int wg   = (int)blockIdx.x;
  const int tid  = (int)threadIdx.x;
  const int lane = tid & 63;
  const int wave = tid >> 6;
  const int rep  = wg & (NREP - 1);
  const int copy = (wg >> 2) & 3;
  const int k0   = 512 * wave + 8 * lane;   // this thread's k-slice

  // W2 for all 8 WG rows x my 8 k values: 64 VGPRs, register-pinned.
  float w2[64];
#pragma unroll
  for (int r = 0; r < 8; ++r) {
    *(float4*)&w2[r * 8]     = *(const float4*)(W2 + (size_t)(wg * RPW + r) * DD + k0);
    *(float4*)&w2[r * 8 + 4] = *(const float4*)(W2 + (size_t)(wg * RPW + r) * DD + k0 + 4);
  }
  // Combine constants for threads 0..15: c = tid&3 -> rows 2c, 2c+1.
  float b2a = 0.f, b2b = 0.f;
  if (tid < 16) {
    const int c = tid & 3;
    b2a = b2[wg * RPW + 2 * c];
    b2b = b2[wg * RPW + 2 * c + 1];
  }

  for (int t = 0; t < TT; ++t) {
    // Prefetch pre pair for the combine (threads 0..15), issued pre-poll.
    float2 p2 = {0.f, 0.f};
    if (tid < 16) p2 = *(const float2*)(pre + (size_t)t * DD + wg * RPW + 2 * (tid & 3));

    float h[8];
    if (t == 0) {
      const float4 a = *(const float4*)(h0 + k0);
      const float4 b = *(const float4*)(h0 + k0 + 4);
      h[0]=a.x; h[1]=a.y; h[2]=a.z; h[3]=a.w;
      h[4]=b.x; h[5]=b.y; h[6]=b.z; h[7]=b.w;
    } else {
      u64* src = hbU + (size_t)(((t & 1) * NREP + rep) * NWG + tid) * 16 + copy * 4;
      const u64 EXP = ((t >> 1) & 1) ? SIGN2 : 0ULL;
      u64 u0, u1, u2, u3;
      for (;;) {
        u0 = aload(src + 0); u1 = aload(src + 1);
        u2 = aload(src + 2); u3 = aload(src + 3);
        if (((((u0 ^ EXP) | (u1 ^ EXP)) | ((u2 ^ EXP) | (u3 ^ EXP))) & SIGN2) == 0ULL)
          break;
        __builtin_amdgcn_s_sleep(1);
      }
      u0 &= ~SIGN2; u1 &= ~SIGN2; u2 &= ~SIGN2; u3 &= ~SIGN2;
      h[0]=__uint_as_float((unsigned)u0); h[1]=__uint_as_float((unsigned)(u0>>32));
      h[2]=__uint_as_float((unsigned)u1); h[3]=__uint_as_float((unsigned)(u1>>32));
      h[4]=__uint_as_float((unsigned)u2); h[5]=__uint_as_float((unsigned)(u2>>32));
      h[6]=__uint_as_float((unsigned)u3); h[7]=__uint_as_float((unsigned)(u3>>32));
    }

    // Straight-from-registers partial GEMV: 8 rows x my 8 k.
    float acc[8];
#pragma unroll
    for (int r = 0; r < 8; ++r) acc[r] = 0.f;
#pragma unroll
    for (int i = 0; i < 8; ++i)
#pragma unroll
      for (int r = 0; r < 8; ++r) acc[r] += w2[r * 8 + i] * h[i];

#pragma unroll
    for (int r = 0; r < 8; ++r) acc[r] = wave_sum(acc[r]);

    if (lane == 0) {
      *(float4*)&partial[t & 1][wave][0] = make_float4(acc[0], acc[1], acc[2], acc[3]);
      *(float4*)&partial[t & 1][wave][4] = make_float4(acc[4], acc[5], acc[6], acc[7]);
    }
    __syncthreads();   // the only barrier per step (partials double-buffered)

    if (tid < 16) {
      const int c = tid & 3;
      const float* P = &partial[t & 1][0][0];
      const float s0 = P[0*8+2*c] + P[1*8+2*c] + P[2*8+2*c] + P[3*8+2*c];
      const float s1 = P[0*8+2*c+1] + P[1*8+2*c+1] + P[2*8+2*c+1] + P[3*8+2*c+1];
      const float v0 = fmaxf(p2.x + b2a + s0, 0.f);
      const float v1 = fmaxf(p2.y + b2b + s1, 0.f);
      u64 u = (((u64)__float_as_uint(v1) << 32) | (u64)__float_as_uint(v0)) & ~SIGN2;
      if (((t + 1) >> 1) & 1) u |= SIGN2;
      // One full 128-B line per replica (16 threads coalesce; u64 j holds
      // rows (2*(j&3), 2*(j&3)+1), j>>2 = intra-line copy).
      u64* base = hbU + (size_t)(((t + 1) & 1) * NREP) * NWG * 16 + (size_t)wg * 16 + tid;
#pragma unroll
      for (int rp = 0; rp < NREP; ++rp) astore(base + (size_t)rp * NWG * 16, u);
    }
  }

  if (wg != 0) return;

  // WG0 epilogue: out = Wf @ h_TT + bf. h_8192: slot 0, rep 0, copy 0, tag 0.
  {
    u64* src = hbU + (size_t)tid * 16;
    u64 u0, u1, u2, u3;
    for (;;) {
      u0 = aload(src + 0); u1 = aload(src + 1);
      u2 = aload(src + 2); u3 = aload(src + 3);
      if ((((u0 | u1) | (u2 | u3)) & SIGN2) == 0ULL) break;
      __builtin_amdgcn_s_sleep(1);
    }
    u64* dst = (u64*)hs + 4 * tid;
    dst[0] = u0; dst[1] = u1; dst[2] = u2; dst[3] = u3;
  }
  __syncthreads();
  float acc = 0.f;
#pragma unroll
  for (int j = 0; j < 8; ++j) {
    const float4 wv = *(const float4*)(Wf + (size_t)wave * DD + j * 256 + 4 * lane);
    const float4 hv = *(const float4*)&hs[j * 256 + 4 * lane];
    acc += wv.x * hv.x + wv.y * hv.y + wv.z * hv.z + wv.w * hv.w;
  }
  acc = wave_sum(acc);
  if (lane == 0) out[wave] = acc + bf[wave];
}

// ---------------- Launch ----------------------------------------------------
extern "C" void kernel_launch(void* const* d_in, const int* in_sizes, int n_in,
                              void* d_out, int out_size, void* d_ws, size_t ws_size,
                              hipStream_t stream) {
  const float* x  = (const float*)d_in[0];
  const float* h0 = (const float*)d_in[1];
  const float* W1 = (const float*)d_in[2];
  const float* b1 = (const float*)d_in[3];
  const float* W2 = (const float*)d_in[4];
  const float* b2 = (const float*)d_in[5];
  const float* Wf = (const float*)d_in[6];
  const float* bf = (const float*)d_in[7];
  float* out = (float*)d_out;

  // Workspace: pre (64 MB) | hbuf (2 slots x NREP x NWG x 128 B = 256 KB)
  float* pre = (float*)d_ws;
  u64*   hbU = (u64*)(pre + (size_t)TT * DD);
  const size_t slot_bytes = (size_t)NREP * NWG * 128;

  // Anti-poison slot init (see kernel comment).
  hipMemsetAsync(hbU, 0x00, slot_bytes, stream);                           // slot0
  hipMemsetAsync((char*)hbU + slot_bytes, 0xAA, slot_bytes, stream);       // slot1

  gemm_abt_bias<<<dim3((TT / BM) * (DD / BN)), dim3(NTH), 0, stream>>>(
      x, W1, b1, pre, TT, DD, DD);
  recurrent_kernel<<<dim3(NWG), dim3(NTH), 0, stream>>>(
      h0, W2, b2, pre, Wf, bf, out, hbU);
}

// Round 7
// 30861.771 us; speedup vs baseline: 1.1874x; 1.1874x over previous
//
#include <hip/hip_runtime.h>

#define TT 8192
#define DD 2048
#define NWG 128
#define RPW 16          // rows of h per workgroup
#define NTH 512
#define NREP 2          // replica buffers to spread LLC poll load

typedef unsigned long long u64;
#define SIGN2 0x8000000080000000ULL

// ---------------- Phase 1: pre = x @ W1^T + b1  (M=TT, N=DD, K=DD) ----------
#define BM 128
#define BN 128
#define BK 16

__global__ __launch_bounds__(256)
void gemm_abt_bias(const float* __restrict__ A, const float* __restrict__ B,
                   const float* __restrict__ bias, float* __restrict__ C,
                   int M, int N, int K) {
  __shared__ float As[BK][BM + 4];
  __shared__ float Bs[BK][BN + 4];
  const int ntile = N / BN;
  const int bn = blockIdx.x % ntile;
  const int bm = blockIdx.x / ntile;
  const int tid = (int)threadIdx.x;
  const int tx = tid & 15;
  const int ty = tid >> 4;

  float acc[8][8];
#pragma unroll
  for (int i = 0; i < 8; ++i)
#pragma unroll
    for (int j = 0; j < 8; ++j) acc[i][j] = 0.f;

  for (int kt = 0; kt < K; kt += BK) {
#pragma unroll
    for (int i = 0; i < 2; ++i) {
      int f = tid + i * 256;
      int row = f >> 2, c4 = f & 3;
      const float4 av = *(const float4*)(A + (size_t)(bm * BM + row) * K + kt + c4 * 4);
      As[c4 * 4 + 0][row] = av.x; As[c4 * 4 + 1][row] = av.y;
      As[c4 * 4 + 2][row] = av.z; As[c4 * 4 + 3][row] = av.w;
      const float4 bv = *(const float4*)(B + (size_t)(bn * BN + row) * K + kt + c4 * 4);
      Bs[c4 * 4 + 0][row] = bv.x; Bs[c4 * 4 + 1][row] = bv.y;
      Bs[c4 * 4 + 2][row] = bv.z; Bs[c4 * 4 + 3][row] = bv.w;
    }
    __syncthreads();
#pragma unroll
    for (int kk = 0; kk < BK; ++kk) {
      float a[8], b[8];
      *(float4*)&a[0] = *(const float4*)&As[kk][ty * 8];
      *(float4*)&a[4] = *(const float4*)&As[kk][ty * 8 + 4];
      *(float4*)&b[0] = *(const float4*)&Bs[kk][tx * 8];
      *(float4*)&b[4] = *(const float4*)&Bs[kk][tx * 8 + 4];
#pragma unroll
      for (int i = 0; i < 8; ++i)
#pragma unroll
        for (int j = 0; j < 8; ++j) acc[i][j] += a[i] * b[j];
    }
    __syncthreads();
  }

  const int col0 = bn * BN + tx * 8;
  const float4 bv0 = *(const float4*)(bias + col0);
  const float4 bv1 = *(const float4*)(bias + col0 + 4);
#pragma unroll
  for (int i = 0; i < 8; ++i) {
    float* crow = C + (size_t)(bm * BM + ty * 8 + i) * N + col0;
    float4 v0 = { acc[i][0] + bv0.x, acc[i][1] + bv0.y, acc[i][2] + bv0.z, acc[i][3] + bv0.w };
    float4 v1 = { acc[i][4] + bv1.x, acc[i][5] + bv1.y, acc[i][6] + bv1.z, acc[i][7] + bv1.w };
    *(float4*)(crow) = v0;
    *(float4*)(crow + 4) = v1;
  }
}

// ---------------- Phase 2: persistent recurrent kernel ----------------------
__device__ __forceinline__ float wave_sum(float v) {
#pragma unroll
  for (int off = 32; off > 0; off >>= 1) v += __shfl_down(v, off, 64);
  return v;
}

__device__ __forceinline__ u64 aload(const u64* p) {
  return __hip_atomic_load(p, __ATOMIC_RELAXED, __HIP_MEMORY_SCOPE_AGENT);
}
__device__ __forceinline__ void astore(u64* p, u64 v) {
  __hip_atomic_store(p, v, __ATOMIC_RELAXED, __HIP_MEMORY_SCOPE_AGENT);
}

// Sync protocol (measured-safe primitives ONLY: relaxed agent-scope atomics;
// parity tags ride in the sign bits of the ReLU-nonnegative h values;
// slot = t&1, tag = (t>>1)&1):
//  * 128 WGs x 512 threads; WG owns 16 rows. h (2048 floats = 1024 u64) is
//    exchanged as tagged u64 row-pairs.
//  * Consumer thread tid's k-slice = [4*tid, 4*tid+4) = u64s {2*tid, 2*tid+1}
//    of its replica -> poll volley is TWO 8B loads (R4 had four): halves
//    chip-wide poll traffic and shortens the tag-check chain.
//  * NREP=2 replicas; consumer polls replica wg&1 -> 64 pollers/address.
//  * Producer: threads 0..7 pack row pairs (2j, 2j+1), tag, and store to both
//    replicas: 16 stores x 8B per WG per step.
//  * ABA/slot-reuse (induction, as R2-R5): any h_{t+2} chunk existing implies
//    every WG stored h_{t+1}, hence finished reading h_t. Tag check and
//    consumption use the same registers (no re-read).
//  * Anti-poison: slot0 = 0x00 (tag 0; first tenant h_2 expects tag 1),
//    slot1 = 0xAA (tag 1; first tenant h_1 expects tag 0).
__global__ void __launch_bounds__(NTH, 2)
recurrent_kernel(const float* __restrict__ h0,
                 const float* __restrict__ W2,
                 const float* __restrict__ b2,
                 const float* __restrict__ pre,
                 const float* __restrict__ Wf,
                 const float* __restrict__ bf,
                 float* __restrict__ out,
                 u64* __restrict__ hb) {   // [slot][rep][DD/2] u64 = 32 KB
  __shared__ float partial[2][8][RPW];    // [t&1][wave][row] (double-buffered)
  __shared__ float hs[DD];                // epilogue only

  const int wg   = (int)blockIdx.x;
  const int tid  = (int)threadIdx.x;
  const int lane = tid & 63;
  const int wave = tid >> 6;              // 8 waves; wave w covers k [256w,256w+256)
  const int rep  = wg & (NREP - 1);
  const int k0   = 4 * tid;               // this thread's k-slice

  // W2 for all 16 WG rows x my 4 k values (64 VGPRs; cap is 256 at 2 waves/EU).
  float4 w2[RPW];
#pragma unroll
  for (int r = 0; r < RPW; ++r)
    w2[r] = *(const float4*)(W2 + (size_t)(wg * RPW + r) * DD + k0);

  // Combine constants for threads 0..7 (row pair 2*tid, 2*tid+1).
  float2 b2p = {0.f, 0.f};
  if (tid < 8) b2p = *(const float2*)(b2 + wg * RPW + 2 * tid);

  for (int t = 0; t < TT; ++t) {
    // Prefetch pre pair for the combine (threads 0..7), issued pre-poll.
    float2 p2 = {0.f, 0.f};
    if (tid < 8) p2 = *(const float2*)(pre + (size_t)t * DD + wg * RPW + 2 * tid);

    float4 h4;
    if (t == 0) {
      h4 = *(const float4*)(h0 + k0);
    } else {
      const u64* src = hb + ((size_t)(t & 1) * NREP + rep) * (DD / 2) + 2 * tid;
      const u64 EXP = ((t >> 1) & 1) ? SIGN2 : 0ULL;
      u64 u0, u1;
      for (;;) {
        u0 = aload(src + 0); u1 = aload(src + 1);
        if ((((u0 ^ EXP) | (u1 ^ EXP)) & SIGN2) == 0ULL) break;
        __builtin_amdgcn_s_sleep(1);
      }
      u0 &= ~SIGN2; u1 &= ~SIGN2;
      h4.x = __uint_as_float((unsigned)u0);
      h4.y = __uint_as_float((unsigned)(u0 >> 32));
      h4.z = __uint_as_float((unsigned)u1);
      h4.w = __uint_as_float((unsigned)(u1 >> 32));
    }

    // Partial GEMV straight from registers: 16 rows x my 4 k.
    float acc[RPW];
#pragma unroll
    for (int r = 0; r < RPW; ++r)
      acc[r] = w2[r].x * h4.x + w2[r].y * h4.y + w2[r].z * h4.z + w2[r].w * h4.w;

#pragma unroll
    for (int r = 0; r < RPW; ++r) acc[r] = wave_sum(acc[r]);

    if (lane == 0) {
#pragma unroll
      for (int q = 0; q < 4; ++q)
        *(float4*)&partial[t & 1][wave][4 * q] =
            make_float4(acc[4*q], acc[4*q+1], acc[4*q+2], acc[4*q+3]);
    }
    __syncthreads();   // the only barrier per step (partials double-buffered)

    if (tid < 8) {
      const int r0 = 2 * tid, r1 = 2 * tid + 1;
      float s0 = 0.f, s1 = 0.f;
#pragma unroll
      for (int w = 0; w < 8; ++w) {
        s0 += partial[t & 1][w][r0];
        s1 += partial[t & 1][w][r1];
      }
      const float v0 = fmaxf(p2.x + b2p.x + s0, 0.f);
      const float v1 = fmaxf(p2.y + b2p.y + s1, 0.f);
      u64 u = (((u64)__float_as_uint(v1) << 32) | (u64)__float_as_uint(v0)) & ~SIGN2;
      if (((t + 1) >> 1) & 1) u |= SIGN2;   // tag for this slot-tenancy
      u64* dst = hb + (size_t)((t + 1) & 1) * NREP * (DD / 2) + (size_t)wg * (RPW / 2) + tid;
      astore(dst, u);                 // replica 0
      astore(dst + (DD / 2), u);      // replica 1
    }
  }

  if (wg != 0) return;

  // WG0 epilogue: out = Wf @ h_TT + bf. h_8192: slot 0, rep 0, tag 0.
  {
    const u64* src = hb + 2 * tid;
    u64 u0, u1;
    for (;;) {
      u0 = aload(src + 0); u1 = aload(src + 1);
      if (((u0 | u1) & SIGN2) == 0ULL) break;   // expect tag 0
      __builtin_amdgcn_s_sleep(1);
    }
    u64* dst = (u64*)hs + 2 * tid;
    dst[0] = u0; dst[1] = u1;
  }
  __syncthreads();
  if (wave < 4) {
    float acc = 0.f;
#pragma unroll
    for (int j = 0; j < 8; ++j) {
      const float4 wv = *(const float4*)(Wf + (size_t)wave * DD + j * 256 + 4 * lane);
      const float4 hv = *(const float4*)&hs[j * 256 + 4 * lane];
      acc += wv.x * hv.x + wv.y * hv.y + wv.z * hv.z + wv.w * hv.w;
    }
    acc = wave_sum(acc);
    if (lane == 0) out[wave] = acc + bf[wave];
  }
}

// ---------------- Launch ----------------------------------------------------
extern "C" void kernel_launch(void* const* d_in, const int* in_sizes, int n_in,
                              void* d_out, int out_size, void* d_ws, size_t ws_size,
                              hipStream_t stream) {
  const float* x  = (const float*)d_in[0];
  const float* h0 = (const float*)d_in[1];
  const float* W1 = (const float*)d_in[2];
  const float* b1 = (const float*)d_in[3];
  const float* W2 = (const float*)d_in[4];
  const float* b2 = (const float*)d_in[5];
  const float* Wf = (const float*)d_in[6];
  const float* bf = (const float*)d_in[7];
  float* out = (float*)d_out;

  // Workspace: pre (64 MB) | hb (2 slots x NREP x DD/2 u64 = 32 KB)
  float* pre = (float*)d_ws;
  u64*   hb  = (u64*)(pre + (size_t)TT * DD);
  const size_t slot_bytes = (size_t)NREP * (DD / 2) * sizeof(u64);   // 16 KB

  // Anti-poison slot init (see kernel comment).
  hipMemsetAsync(hb, 0x00, slot_bytes, stream);                      // slot 0
  hipMemsetAsync((char*)hb + slot_bytes, 0xAA, slot_bytes, stream);  // slot 1

  gemm_abt_bias<<<dim3((TT / BM) * (DD / BN)), dim3(256), 0, stream>>>(
      x, W1, b1, pre, TT, DD, DD);
  recurrent_kernel<<<dim3(NWG), dim3(NTH), 0, stream>>>(
      h0, W2, b2, pre, Wf, bf, out, hb);
}